// Round 5
// baseline (447.679 us; speedup 1.0000x reference)
//
#include <hip/hip_runtime.h>
#include <cstdint>

#define DIN 512
#define DH  256
#define DOUT 64

typedef __attribute__((ext_vector_type(8))) short bf16x8;
typedef __attribute__((ext_vector_type(4))) float f32x4;
typedef unsigned int uint32;

__device__ __forceinline__ unsigned short f2bf(float f) {
    uint32 u = __float_as_uint(f);
    u += 0x7fff + ((u >> 16) & 1);          // RNE
    return (unsigned short)(u >> 16);
}
__device__ __forceinline__ float bflo(uint32 u) { return __uint_as_float(u << 16); }
__device__ __forceinline__ float bfhi(uint32 u) { return __uint_as_float(u & 0xffff0000u); }
__device__ __forceinline__ uint32 pk2(float lo, float hi) {
    return (uint32)f2bf(lo) | ((uint32)f2bf(hi) << 16);
}

// ---------------- edge_index dtype detection ----------------
__global__ void detect_i64(const unsigned long long* ei, int n_check,
                           unsigned long long bound, int* flag) {
    __shared__ int ok;
    if (threadIdx.x == 0) ok = 1;
    __syncthreads();
    int bad = 0;
    for (int i = threadIdx.x; i < n_check; i += blockDim.x) {
        if (ei[i] >= bound) bad = 1;
    }
    if (bad) ok = 0;
    __syncthreads();
    if (threadIdx.x == 0) *flag = ok;
}

__device__ __forceinline__ int get_idx(const void* ei, int is64, int pos) {
    if (is64) return (int)((const long long*)ei)[pos];
    return ((const int*)ei)[pos];
}

// ---------------- degree count / dinv ----------------
__global__ void count_deg(const void* ei, const int* flag, int E, int* counts) {
    const int is64 = *flag;
    int e = blockIdx.x * blockDim.x + threadIdx.x;
    if (e >= E) return;
    int d = get_idx(ei, is64, E + e);
    atomicAdd(&counts[d], 1);
}

__global__ void compute_dinv(const int* counts, float* dinv, int N) {
    int i = blockIdx.x * blockDim.x + threadIdx.x;
    if (i < N) dinv[i] = rsqrtf((float)counts[i] + 1.0f);
}

// ---------------- exclusive scan ----------------
#define SCAN_BLOCK 256
#define SCAN_ELEMS 1024

__global__ void scan1(const int* counts, int* out, int* blocksums, int N) {
    __shared__ int sh[SCAN_BLOCK];
    int base = blockIdx.x * SCAN_ELEMS;
    int t = threadIdx.x;
    int v[4];
    int s = 0;
    #pragma unroll
    for (int j = 0; j < 4; j++) {
        int idx = base + t * 4 + j;
        v[j] = (idx < N) ? counts[idx] : 0;
        s += v[j];
    }
    sh[t] = s;
    __syncthreads();
    for (int off = 1; off < SCAN_BLOCK; off <<= 1) {
        int x = (t >= off) ? sh[t - off] : 0;
        __syncthreads();
        sh[t] += x;
        __syncthreads();
    }
    int run = (t == 0) ? 0 : sh[t - 1];
    #pragma unroll
    for (int j = 0; j < 4; j++) {
        int idx = base + t * 4 + j;
        if (idx < N) out[idx] = run;
        run += v[j];
    }
    if (t == SCAN_BLOCK - 1) blocksums[blockIdx.x] = sh[t];
}

__global__ void scan2(int* blocksums, int NB) {
    __shared__ int sh[SCAN_BLOCK];
    int t = threadIdx.x;
    sh[t] = (t < NB) ? blocksums[t] : 0;
    __syncthreads();
    for (int off = 1; off < SCAN_BLOCK; off <<= 1) {
        int x = (t >= off) ? sh[t - off] : 0;
        __syncthreads();
        sh[t] += x;
        __syncthreads();
    }
    if (t < NB) blocksums[t] = (t == 0) ? 0 : sh[t - 1];
}

__global__ void scan3(int* row_ptr, const int* blocksums, int N, int E) {
    int i = blockIdx.x * blockDim.x + threadIdx.x;
    if (i < N) row_ptr[i] += blocksums[i / SCAN_ELEMS];
    if (i == N) row_ptr[N] = E;
}

// ---------------- CSR fill (+ per-edge weight) ----------------
__global__ void fill_csr(const void* ei, const int* flag, int E,
                         const int* row_ptr, int* cursor, int* col_idx,
                         const float* dinv, float* edge_w) {
    const int is64 = *flag;
    int e = blockIdx.x * blockDim.x + threadIdx.x;
    if (e >= E) return;
    int d = get_idx(ei, is64, E + e);
    int s = get_idx(ei, is64, e);
    int pos = row_ptr[d] + atomicAdd(&cursor[d], 1);
    col_idx[pos] = s;
    edge_w[pos] = dinv[s] * dinv[d];
}

// ---------------- weight transpose+convert: W[K][Nw] f32 -> Bt[Nw][K] bf16 ----------------
__global__ void transpose_w(const float* __restrict__ W, unsigned short* __restrict__ Bt,
                            int K, int Nw) {
    int i = blockIdx.x * blockDim.x + threadIdx.x;
    if (i >= K * Nw) return;
    int k = i / Nw, n = i % Nw;
    Bt[(size_t)n * K + k] = f2bf(W[i]);
}

// ---------------- GEMM1: C[M,256] = bf16(A_f32[M,K]) @ Bt[256,K]^T ----------------
// BM=64 BN=256, 4 waves. A reg-staged fp32->bf16 into swizzled LDS;
// B fragments read DIRECTLY from global (L2-resident weights). 32 KB LDS.
__global__ __launch_bounds__(256) void gemm1_mfma(const float* __restrict__ Af,
                                                  const unsigned short* __restrict__ Bt,
                                                  unsigned short* __restrict__ C,
                                                  int M, int K) {
    __shared__ unsigned short lds[16384];   // As = first 4096; epilogue uses all
    unsigned short* As = lds;
    const int tid = threadIdx.x;
    const int w = tid >> 6, l = tid & 63;
    const int m0 = blockIdx.x * 64;

    f32x4 acc[4][4] = {};

    for (int k0 = 0; k0 < K; k0 += 64) {
        __syncthreads();    // As free of previous-iter readers
        #pragma unroll
        for (int i = 0; i < 2; i++) {
            int row = i * 32 + (tid >> 3);
            int g = tid & 7;
            int rg = m0 + row; if (rg > M - 1) rg = M - 1;
            const float* s = Af + (size_t)rg * K + k0 + g * 8;
            float4 v0 = *(const float4*)s;
            float4 v1 = *(const float4*)(s + 4);
            uint4 o;
            o.x = pk2(v0.x, v0.y); o.y = pk2(v0.z, v0.w);
            o.z = pk2(v1.x, v1.y); o.w = pk2(v1.z, v1.w);
            *(uint4*)(As + row * 64 + ((g ^ (row & 7)) * 8)) = o;
        }
        __syncthreads();
        #pragma unroll
        for (int ks = 0; ks < 2; ks++) {
            bf16x8 a[4], b[4];
            #pragma unroll
            for (int m = 0; m < 4; m++) {
                int ar = m * 16 + (l & 15);
                int q = (ks * 4 + (l >> 4)) ^ (ar & 7);
                a[m] = *(const bf16x8*)(As + ar * 64 + q * 8);
            }
            #pragma unroll
            for (int n = 0; n < 4; n++) {
                int br = w * 64 + n * 16 + (l & 15);
                b[n] = *(const bf16x8*)(Bt + (size_t)br * K + k0 + ks * 32 + (l >> 4) * 8);
            }
            #pragma unroll
            for (int m = 0; m < 4; m++)
                #pragma unroll
                for (int n = 0; n < 4; n++)
                    acc[m][n] = __builtin_amdgcn_mfma_f32_16x16x32_bf16(a[m], b[n], acc[m][n], 0, 0, 0);
        }
    }
    __syncthreads();
    unsigned short* ep = lds + w * 4096;
    #pragma unroll
    for (int m = 0; m < 4; m++)
        #pragma unroll
        for (int n = 0; n < 4; n++)
            #pragma unroll
            for (int r = 0; r < 4; r++)
                ep[(m * 16 + (l >> 4) * 4 + r) * 64 + n * 16 + (l & 15)] = f2bf(acc[m][n][r]);
    __syncthreads();
    #pragma unroll
    for (int p = 0; p < 8; p++) {
        int row = p * 8 + (l >> 3);
        int gr = m0 + row;
        uint4 v = *(const uint4*)(ep + row * 64 + (l & 7) * 8);
        if (gr < M)
            *(uint4*)(C + (size_t)gr * 256 + w * 64 + (l & 7) * 8) = v;
    }
}

// ---------------- aggregation body (32-lane half, 8 feats/lane) ----------------
#define ACC8(v, wgt)                                    \
    do {                                                \
        acc[0] = fmaf(wgt, bflo(v.x), acc[0]);          \
        acc[1] = fmaf(wgt, bfhi(v.x), acc[1]);          \
        acc[2] = fmaf(wgt, bflo(v.y), acc[2]);          \
        acc[3] = fmaf(wgt, bfhi(v.y), acc[3]);          \
        acc[4] = fmaf(wgt, bflo(v.z), acc[4]);          \
        acc[5] = fmaf(wgt, bfhi(v.z), acc[5]);          \
        acc[6] = fmaf(wgt, bflo(v.w), acc[6]);          \
        acc[7] = fmaf(wgt, bfhi(v.w), acc[7]);          \
    } while (0)

// Aggregate node n (feats sl*8..sl*8+7) from t, relu(x+bias), return packed bf16x8.
__device__ __forceinline__ uint4 agg_row(const unsigned short* __restrict__ t,
                                         const float* __restrict__ dinv,
                                         const int* __restrict__ row_ptr,
                                         const int* __restrict__ col_idx,
                                         const float* __restrict__ edge_w,
                                         const float* __restrict__ bias,
                                         int n, int sl) {
    float dn = dinv[n];
    int r0 = row_ptr[n], r1 = row_ptr[n + 1];
    float acc[8];
    {
        uint4 sv = *(const uint4*)(t + (size_t)n * DH + sl * 8);
        float sn = dn * dn;
        acc[0] = bflo(sv.x) * sn; acc[1] = bfhi(sv.x) * sn;
        acc[2] = bflo(sv.y) * sn; acc[3] = bfhi(sv.y) * sn;
        acc[4] = bflo(sv.z) * sn; acc[5] = bfhi(sv.z) * sn;
        acc[6] = bflo(sv.w) * sn; acc[7] = bfhi(sv.w) * sn;
    }
    int j = r0;
    for (; j + 4 <= r1; j += 4) {
        int s0 = col_idx[j + 0], s1 = col_idx[j + 1];
        int s2 = col_idx[j + 2], s3 = col_idx[j + 3];
        float w0 = edge_w[j + 0], w1 = edge_w[j + 1];
        float w2 = edge_w[j + 2], w3 = edge_w[j + 3];
        uint4 v0 = *(const uint4*)(t + (size_t)s0 * DH + sl * 8);
        uint4 v1 = *(const uint4*)(t + (size_t)s1 * DH + sl * 8);
        uint4 v2 = *(const uint4*)(t + (size_t)s2 * DH + sl * 8);
        uint4 v3 = *(const uint4*)(t + (size_t)s3 * DH + sl * 8);
        ACC8(v0, w0); ACC8(v1, w1); ACC8(v2, w2); ACC8(v3, w3);
    }
    for (; j < r1; j++) {
        int s = col_idx[j];
        float wgt = edge_w[j];
        uint4 v = *(const uint4*)(t + (size_t)s * DH + sl * 8);
        ACC8(v, wgt);
    }
    float4 b0 = *(const float4*)(bias + sl * 8);
    float4 b1v = *(const float4*)(bias + sl * 8 + 4);
    acc[0] = fmaxf(acc[0] + b0.x, 0.f);  acc[1] = fmaxf(acc[1] + b0.y, 0.f);
    acc[2] = fmaxf(acc[2] + b0.z, 0.f);  acc[3] = fmaxf(acc[3] + b0.w, 0.f);
    acc[4] = fmaxf(acc[4] + b1v.x, 0.f); acc[5] = fmaxf(acc[5] + b1v.y, 0.f);
    acc[6] = fmaxf(acc[6] + b1v.z, 0.f); acc[7] = fmaxf(acc[7] + b1v.w, 0.f);
    uint4 o;
    o.x = pk2(acc[0], acc[1]);
    o.y = pk2(acc[2], acc[3]);
    o.z = pk2(acc[4], acc[5]);
    o.w = pk2(acc[6], acc[7]);
    return o;
}

// ---------------- fused: a = relu(agg(t)+bias); C[M,256] = a @ Bt[256,256]^T ----------------
// BM=64, 4 waves. Aggregated A lives in 32 KB swizzled LDS; K-loop barrier-free.
__global__ __launch_bounds__(256) void fused_mid(const unsigned short* __restrict__ t,
                                                 const float* __restrict__ dinv,
                                                 const int* __restrict__ row_ptr,
                                                 const int* __restrict__ col_idx,
                                                 const float* __restrict__ edge_w,
                                                 const float* __restrict__ bias,
                                                 const unsigned short* __restrict__ Bt,
                                                 unsigned short* __restrict__ C,
                                                 int N) {
    __shared__ unsigned short As[16384];   // [64][256] swizzled
    const int tid = threadIdx.x;
    const int w = tid >> 6, l = tid & 63;
    const int half = l >> 5, sl = l & 31;
    const int m0 = blockIdx.x * 64;

    // phase 1: aggregate 64 rows into LDS
    #pragma unroll 1
    for (int i = 0; i < 8; i++) {
        int row = i * 8 + w * 2 + half;
        int n = m0 + row;
        uint4 o = make_uint4(0, 0, 0, 0);
        if (n < N) o = agg_row(t, dinv, row_ptr, col_idx, edge_w, bias, n, sl);
        *(uint4*)(As + row * 256 + ((sl ^ (row & 7)) * 8)) = o;
    }
    __syncthreads();

    // phase 2: GEMM K=256, no barriers
    f32x4 acc[4][4] = {};
    #pragma unroll
    for (int kt = 0; kt < 4; kt++) {
        #pragma unroll
        for (int ks = 0; ks < 2; ks++) {
            bf16x8 a[4], b[4];
            #pragma unroll
            for (int m = 0; m < 4; m++) {
                int ar = m * 16 + (l & 15);
                int q = (kt * 8 + ks * 4 + (l >> 4)) ^ (ar & 7);
                a[m] = *(const bf16x8*)(As + ar * 256 + q * 8);
            }
            #pragma unroll
            for (int n = 0; n < 4; n++) {
                int br = w * 64 + n * 16 + (l & 15);
                b[n] = *(const bf16x8*)(Bt + (size_t)br * 256 + kt * 64 + ks * 32 + (l >> 4) * 8);
            }
            #pragma unroll
            for (int m = 0; m < 4; m++)
                #pragma unroll
                for (int n = 0; n < 4; n++)
                    acc[m][n] = __builtin_amdgcn_mfma_f32_16x16x32_bf16(a[m], b[n], acc[m][n], 0, 0, 0);
        }
    }
    __syncthreads();

    // phase 3: epilogue, reuse As
    unsigned short* ep = As + w * 4096;
    #pragma unroll
    for (int m = 0; m < 4; m++)
        #pragma unroll
        for (int n = 0; n < 4; n++)
            #pragma unroll
            for (int r = 0; r < 4; r++)
                ep[(m * 16 + (l >> 4) * 4 + r) * 64 + n * 16 + (l & 15)] = f2bf(acc[m][n][r]);
    __syncthreads();
    #pragma unroll
    for (int p = 0; p < 8; p++) {
        int row = p * 8 + (l >> 3);
        int gr = m0 + row;
        uint4 v = *(const uint4*)(ep + row * 64 + (l & 7) * 8);
        if (gr < N)
            *(uint4*)(C + (size_t)gr * 256 + w * 64 + (l & 7) * 8) = v;
    }
}

// ---------------- fused head: a = relu(agg(t2)+b2); out[M,64] = a @ Btc[64,256]^T + bc ----------------
__global__ __launch_bounds__(256) void fused_head(const unsigned short* __restrict__ t2,
                                                  const float* __restrict__ dinv,
                                                  const int* __restrict__ row_ptr,
                                                  const int* __restrict__ col_idx,
                                                  const float* __restrict__ edge_w,
                                                  const float* __restrict__ b2,
                                                  const unsigned short* __restrict__ Btc,
                                                  const float* __restrict__ bc,
                                                  float* __restrict__ out,
                                                  int N) {
    __shared__ unsigned short As[16384];   // [64][256] swizzled
    const int tid = threadIdx.x;
    const int w = tid >> 6, l = tid & 63;
    const int half = l >> 5, sl = l & 31;
    const int m0 = blockIdx.x * 64;

    #pragma unroll 1
    for (int i = 0; i < 8; i++) {
        int row = i * 8 + w * 2 + half;
        int n = m0 + row;
        uint4 o = make_uint4(0, 0, 0, 0);
        if (n < N) o = agg_row(t2, dinv, row_ptr, col_idx, edge_w, b2, n, sl);
        *(uint4*)(As + row * 256 + ((sl ^ (row & 7)) * 8)) = o;
    }
    __syncthreads();

    // wave w owns rows w*16..w*16+15, all 64 output cols
    f32x4 acc[4] = {};
    #pragma unroll
    for (int kt = 0; kt < 4; kt++) {
        #pragma unroll
        for (int ks = 0; ks < 2; ks++) {
            int ar = w * 16 + (l & 15);
            int q = (kt * 8 + ks * 4 + (l >> 4)) ^ (ar & 7);
            bf16x8 a = *(const bf16x8*)(As + ar * 256 + q * 8);
            bf16x8 b[4];
            #pragma unroll
            for (int n = 0; n < 4; n++) {
                int br = n * 16 + (l & 15);
                b[n] = *(const bf16x8*)(Btc + (size_t)br * 256 + kt * 64 + ks * 32 + (l >> 4) * 8);
            }
            #pragma unroll
            for (int n = 0; n < 4; n++)
                acc[n] = __builtin_amdgcn_mfma_f32_16x16x32_bf16(a, b[n], acc[n], 0, 0, 0);
        }
    }
    #pragma unroll
    for (int n = 0; n < 4; n++)
        #pragma unroll
        for (int r = 0; r < 4; r++) {
            int gr = m0 + w * 16 + (l >> 4) * 4 + r;
            int col = n * 16 + (l & 15);
            if (gr < N) out[(size_t)gr * 64 + col] = acc[n][r] + bc[col];
        }
}

// ---------------- launch ----------------
extern "C" void kernel_launch(void* const* d_in, const int* in_sizes, int n_in,
                              void* d_out, int out_size, void* d_ws, size_t ws_size,
                              hipStream_t stream) {
    const float* x  = (const float*)d_in[0];
    const void*  ei = d_in[1];
    const float* W1 = (const float*)d_in[2];
    const float* b1 = (const float*)d_in[3];
    const float* W2 = (const float*)d_in[4];
    const float* b2 = (const float*)d_in[5];
    const float* Wc = (const float*)d_in[6];
    const float* bc = (const float*)d_in[7];
    float* out = (float*)d_out;

    const int N = in_sizes[0] / DIN;   // 100000
    const int E = in_sizes[1] / 2;     // 800000

    char* ws = (char*)d_ws;
    size_t off = 0;
    auto alloc = [&](size_t bytes) -> void* {
        off = (off + 255) & ~(size_t)255;
        void* p = ws + off;
        off += bytes;
        return p;
    };

    int*   flag      = (int*)alloc(4);
    int*   counts    = (int*)alloc((size_t)N * 4);
    int*   row_ptr   = (int*)alloc((size_t)(N + 1) * 4);
    int*   col_idx   = (int*)alloc((size_t)E * 4);
    float* edge_w    = (float*)alloc((size_t)E * 4);
    int*   blocksums = (int*)alloc(1024 * 4);
    float* dinv      = (float*)alloc((size_t)N * 4);
    unsigned short* Bt1   = (unsigned short*)alloc((size_t)DH * DIN * 2);
    unsigned short* Bt2   = (unsigned short*)alloc((size_t)DH * DH * 2);
    unsigned short* Btc   = (unsigned short*)alloc((size_t)DOUT * DH * 2);
    unsigned short* t_buf = (unsigned short*)alloc((size_t)N * DH * 2);
    unsigned short* t2    = (unsigned short*)alloc((size_t)N * DH * 2);

    const int NB = (N + SCAN_ELEMS - 1) / SCAN_ELEMS;
    const int gM64 = (N + 63) / 64;

    // dtype detection + weight prep
    detect_i64<<<1, 256, 0, stream>>>((const unsigned long long*)ei, 1024,
                                      (unsigned long long)N, flag);
    transpose_w<<<(DIN * DH + 255) / 256, 256, 0, stream>>>(W1, Bt1, DIN, DH);
    transpose_w<<<(DH * DH + 255) / 256, 256, 0, stream>>>(W2, Bt2, DH, DH);
    transpose_w<<<(DH * DOUT + 255) / 256, 256, 0, stream>>>(Wc, Btc, DH, DOUT);

    // degrees + CSR (+ per-edge weights)
    hipMemsetAsync(counts, 0, (size_t)N * 4, stream);
    count_deg<<<(E + 255) / 256, 256, 0, stream>>>(ei, flag, E, counts);
    compute_dinv<<<(N + 255) / 256, 256, 0, stream>>>(counts, dinv, N);
    scan1<<<NB, SCAN_BLOCK, 0, stream>>>(counts, row_ptr, blocksums, N);
    scan2<<<1, SCAN_BLOCK, 0, stream>>>(blocksums, NB);
    scan3<<<(N + 1 + 255) / 256, 256, 0, stream>>>(row_ptr, blocksums, N, E);
    hipMemsetAsync(counts, 0, (size_t)N * 4, stream);
    fill_csr<<<(E + 255) / 256, 256, 0, stream>>>(ei, flag, E, row_ptr, counts, col_idx,
                                                  dinv, edge_w);

    // layer 1 transform
    gemm1_mfma<<<gM64, 256, 0, stream>>>(x, Bt1, t_buf, N, DIN);
    // agg1 + layer 2 transform (fused)
    fused_mid<<<gM64, 256, 0, stream>>>(t_buf, dinv, row_ptr, col_idx, edge_w, b1, Bt2, t2, N);
    // agg2 + head (fused)
    fused_head<<<gM64, 256, 0, stream>>>(t2, dinv, row_ptr, col_idx, edge_w, b2, Btc, bc, out, N);
}

// Round 6
// 387.327 us; speedup vs baseline: 1.1558x; 1.1558x over previous
//
#include <hip/hip_runtime.h>
#include <cstdint>

#define DIN 512
#define DH  256
#define DOUT 64

typedef __attribute__((ext_vector_type(8))) short bf16x8;
typedef __attribute__((ext_vector_type(4))) float f32x4;
typedef unsigned int uint32;

__device__ __forceinline__ unsigned short f2bf(float f) {
    uint32 u = __float_as_uint(f);
    u += 0x7fff + ((u >> 16) & 1);          // RNE
    return (unsigned short)(u >> 16);
}
__device__ __forceinline__ float bflo(uint32 u) { return __uint_as_float(u << 16); }
__device__ __forceinline__ float bfhi(uint32 u) { return __uint_as_float(u & 0xffff0000u); }
__device__ __forceinline__ uint32 pk2(float lo, float hi) {
    return (uint32)f2bf(lo) | ((uint32)f2bf(hi) << 16);
}

// ---------------- edge_index dtype detection ----------------
__global__ void detect_i64(const unsigned long long* ei, int n_check,
                           unsigned long long bound, int* flag) {
    __shared__ int ok;
    if (threadIdx.x == 0) ok = 1;
    __syncthreads();
    int bad = 0;
    for (int i = threadIdx.x; i < n_check; i += blockDim.x) {
        if (ei[i] >= bound) bad = 1;
    }
    if (bad) ok = 0;
    __syncthreads();
    if (threadIdx.x == 0) *flag = ok;
}

__device__ __forceinline__ int get_idx(const void* ei, int is64, int pos) {
    if (is64) return (int)((const long long*)ei)[pos];
    return ((const int*)ei)[pos];
}

// ---------------- degree count / dinv ----------------
__global__ void count_deg(const void* ei, const int* flag, int E, int* counts) {
    const int is64 = *flag;
    int e = blockIdx.x * blockDim.x + threadIdx.x;
    if (e >= E) return;
    int d = get_idx(ei, is64, E + e);
    atomicAdd(&counts[d], 1);
}

__global__ void compute_dinv(const int* counts, float* dinv, int N) {
    int i = blockIdx.x * blockDim.x + threadIdx.x;
    if (i < N) dinv[i] = rsqrtf((float)counts[i] + 1.0f);
}

// ---------------- exclusive scan ----------------
#define SCAN_BLOCK 256
#define SCAN_ELEMS 1024

__global__ void scan1(const int* counts, int* out, int* blocksums, int N) {
    __shared__ int sh[SCAN_BLOCK];
    int base = blockIdx.x * SCAN_ELEMS;
    int t = threadIdx.x;
    int v[4];
    int s = 0;
    #pragma unroll
    for (int j = 0; j < 4; j++) {
        int idx = base + t * 4 + j;
        v[j] = (idx < N) ? counts[idx] : 0;
        s += v[j];
    }
    sh[t] = s;
    __syncthreads();
    for (int off = 1; off < SCAN_BLOCK; off <<= 1) {
        int x = (t >= off) ? sh[t - off] : 0;
        __syncthreads();
        sh[t] += x;
        __syncthreads();
    }
    int run = (t == 0) ? 0 : sh[t - 1];
    #pragma unroll
    for (int j = 0; j < 4; j++) {
        int idx = base + t * 4 + j;
        if (idx < N) out[idx] = run;
        run += v[j];
    }
    if (t == SCAN_BLOCK - 1) blocksums[blockIdx.x] = sh[t];
}

__global__ void scan2(int* blocksums, int NB) {
    __shared__ int sh[SCAN_BLOCK];
    int t = threadIdx.x;
    sh[t] = (t < NB) ? blocksums[t] : 0;
    __syncthreads();
    for (int off = 1; off < SCAN_BLOCK; off <<= 1) {
        int x = (t >= off) ? sh[t - off] : 0;
        __syncthreads();
        sh[t] += x;
        __syncthreads();
    }
    if (t < NB) blocksums[t] = (t == 0) ? 0 : sh[t - 1];
}

__global__ void scan3(int* row_ptr, const int* blocksums, int N, int E) {
    int i = blockIdx.x * blockDim.x + threadIdx.x;
    if (i < N) row_ptr[i] += blocksums[i / SCAN_ELEMS];
    if (i == N) row_ptr[N] = E;
}

// ---------------- CSR fill (+ per-edge weight) ----------------
__global__ void fill_csr(const void* ei, const int* flag, int E,
                         const int* row_ptr, int* cursor, int* col_idx,
                         const float* dinv, float* edge_w) {
    const int is64 = *flag;
    int e = blockIdx.x * blockDim.x + threadIdx.x;
    if (e >= E) return;
    int d = get_idx(ei, is64, E + e);
    int s = get_idx(ei, is64, e);
    int pos = row_ptr[d] + atomicAdd(&cursor[d], 1);
    col_idx[pos] = s;
    edge_w[pos] = dinv[s] * dinv[d];
}

// ---------------- weight transpose+convert: W[K][Nw] f32 -> Bt[Nw][K] bf16 ----------------
__global__ void transpose_w(const float* __restrict__ W, unsigned short* __restrict__ Bt,
                            int K, int Nw) {
    int i = blockIdx.x * blockDim.x + threadIdx.x;
    if (i >= K * Nw) return;
    int k = i / Nw, n = i % Nw;
    Bt[(size_t)n * K + k] = f2bf(W[i]);
}

// ---------------- MFMA GEMM: C[M,256]=A[M,K]*Bt[256,K]^T, bf16 out ----------------
// BM=64 BN=256, 4 waves. A double-buffered in 2x8KB swizzled LDS, ONE barrier
// per K-step (loads for k+1 issued before compute of k). B fragments read
// directly from global (weights are L2-resident). 32 KB LDS total.
template <bool A_FP32>
__global__ __launch_bounds__(256) void gemm_mfma(const void* __restrict__ Ap,
                                                 const unsigned short* __restrict__ Bt,
                                                 unsigned short* __restrict__ C,
                                                 int M, int K) {
    __shared__ unsigned short lds[16384];   // 2x8KB A dbuf; epilogue reuses all 32KB
    const int tid = threadIdx.x;
    const int w = tid >> 6, l = tid & 63;
    const int m0 = blockIdx.x * 64;
    const int nk = K >> 6;

    const float* Af = (const float*)Ap;
    const unsigned short* Ab = (const unsigned short*)Ap;

    f32x4 acc[4][4] = {};
    float4 ra0, ra1, ra2, ra3;              // fp32-path staging regs (2 rows x 32B)

    const int srow0 = (tid >> 3);           // rows srow0, srow0+32
    const int sg = tid & 7;                 // 16B granule within 64-col row
    int rg0 = m0 + srow0;      if (rg0 > M - 1) rg0 = M - 1;
    int rg1 = m0 + srow0 + 32; if (rg1 > M - 1) rg1 = M - 1;

    // ---- prologue: stage tile 0 ----
    if (A_FP32) {
        const float* s0 = Af + (size_t)rg0 * K + sg * 8;
        const float* s1 = Af + (size_t)rg1 * K + sg * 8;
        ra0 = *(const float4*)s0; ra1 = *(const float4*)(s0 + 4);
        ra2 = *(const float4*)s1; ra3 = *(const float4*)(s1 + 4);
        uint4 o0, o1;
        o0.x = pk2(ra0.x, ra0.y); o0.y = pk2(ra0.z, ra0.w);
        o0.z = pk2(ra1.x, ra1.y); o0.w = pk2(ra1.z, ra1.w);
        o1.x = pk2(ra2.x, ra2.y); o1.y = pk2(ra2.z, ra2.w);
        o1.z = pk2(ra3.x, ra3.y); o1.w = pk2(ra3.z, ra3.w);
        *(uint4*)(lds + srow0 * 64 + ((sg ^ (srow0 & 7)) * 8)) = o0;
        *(uint4*)(lds + (srow0 + 32) * 64 + ((sg ^ ((srow0 + 32) & 7)) * 8)) = o1;
    } else {
        #pragma unroll
        for (int i = 0; i < 2; i++) {
            int row = i * 32 + srow0;
            int gq = sg ^ (row & 7);
            int rg = (i == 0) ? rg0 : rg1;
            __builtin_amdgcn_global_load_lds(
                (const __attribute__((address_space(1))) uint32*)(Ab + (size_t)rg * K + gq * 8),
                (__attribute__((address_space(3))) uint32*)(lds + row * 64 + sg * 8), 16, 0, 0);
        }
    }
    __syncthreads();

    for (int k = 0; k < nk; k++) {
        unsigned short* cur = lds + (k & 1) * 4096;
        unsigned short* nxt = lds + ((k + 1) & 1) * 4096;
        const int k0 = k << 6;
        const bool more = (k + 1 < nk);

        // ---- issue A loads for tile k+1 (latency hidden under compute) ----
        if (more) {
            const int k0n = k0 + 64;
            if (A_FP32) {
                const float* s0 = Af + (size_t)rg0 * K + k0n + sg * 8;
                const float* s1 = Af + (size_t)rg1 * K + k0n + sg * 8;
                ra0 = *(const float4*)s0; ra1 = *(const float4*)(s0 + 4);
                ra2 = *(const float4*)s1; ra3 = *(const float4*)(s1 + 4);
            } else {
                #pragma unroll
                for (int i = 0; i < 2; i++) {
                    int row = i * 32 + srow0;
                    int gq = sg ^ (row & 7);
                    int rg = (i == 0) ? rg0 : rg1;
                    __builtin_amdgcn_global_load_lds(
                        (const __attribute__((address_space(1))) uint32*)(Ab + (size_t)rg * K + k0n + gq * 8),
                        (__attribute__((address_space(3))) uint32*)(nxt + row * 64 + sg * 8), 16, 0, 0);
                }
            }
        }

        // ---- compute tile k: A from LDS (swizzled), B direct from global ----
        #pragma unroll
        for (int ks = 0; ks < 2; ks++) {
            bf16x8 a[4], b[4];
            #pragma unroll
            for (int m = 0; m < 4; m++) {
                int ar = m * 16 + (l & 15);
                int q = (ks * 4 + (l >> 4)) ^ (ar & 7);
                a[m] = *(const bf16x8*)(cur + ar * 64 + q * 8);
            }
            #pragma unroll
            for (int n = 0; n < 4; n++) {
                int br = w * 64 + n * 16 + (l & 15);
                b[n] = *(const bf16x8*)(Bt + (size_t)br * K + k0 + ks * 32 + (l >> 4) * 8);
            }
            #pragma unroll
            for (int m = 0; m < 4; m++)
                #pragma unroll
                for (int n = 0; n < 4; n++)
                    acc[m][n] = __builtin_amdgcn_mfma_f32_16x16x32_bf16(a[m], b[n], acc[m][n], 0, 0, 0);
        }

        // ---- fp32 path: convert + store staged regs into nxt ----
        if (A_FP32 && more) {
            uint4 o0, o1;
            o0.x = pk2(ra0.x, ra0.y); o0.y = pk2(ra0.z, ra0.w);
            o0.z = pk2(ra1.x, ra1.y); o0.w = pk2(ra1.z, ra1.w);
            o1.x = pk2(ra2.x, ra2.y); o1.y = pk2(ra2.z, ra2.w);
            o1.z = pk2(ra3.x, ra3.y); o1.w = pk2(ra3.z, ra3.w);
            *(uint4*)(nxt + srow0 * 64 + ((sg ^ (srow0 & 7)) * 8)) = o0;
            *(uint4*)(nxt + (srow0 + 32) * 64 + ((sg ^ ((srow0 + 32) & 7)) * 8)) = o1;
        }
        __syncthreads();
    }

    // ---- epilogue: per-wave 64x64 region in LDS -> coalesced 16B stores ----
    unsigned short* ep = lds + w * 4096;
    #pragma unroll
    for (int m = 0; m < 4; m++)
        #pragma unroll
        for (int n = 0; n < 4; n++)
            #pragma unroll
            for (int r = 0; r < 4; r++)
                ep[(m * 16 + (l >> 4) * 4 + r) * 64 + n * 16 + (l & 15)] = f2bf(acc[m][n][r]);
    __syncthreads();
    #pragma unroll
    for (int p = 0; p < 8; p++) {
        int row = p * 8 + (l >> 3);
        int gr = m0 + row;
        uint4 v = *(const uint4*)(ep + row * 64 + (l & 7) * 8);
        if (gr < M)
            *(uint4*)(C + (size_t)gr * 256 + w * 64 + (l & 7) * 8) = v;
    }
}

// ---------------- head GEMM: out[M,64] = A[M,256]*Bt[64,256]^T + bias, f32 out ----------------
__global__ __launch_bounds__(256) void gemm_head(const unsigned short* __restrict__ A,
                                                 const unsigned short* __restrict__ Bt,
                                                 const float* __restrict__ bias,
                                                 float* __restrict__ out, int M) {
    __shared__ unsigned short As[128 * 64];
    __shared__ unsigned short Bs[64 * 64];
    const int tid = threadIdx.x;
    const int w = tid >> 6, l = tid & 63;
    const int m0 = blockIdx.x * 128;
    const int wr = w >> 1, wc = w & 1;
    f32x4 acc[4][2] = {};

    for (int k0 = 0; k0 < 256; k0 += 64) {
        #pragma unroll
        for (int i = 0; i < 4; i++) {
            int row = i * 32 + (tid >> 3);
            int gq = (tid & 7) ^ (row & 7);
            int rg = m0 + row; if (rg > M - 1) rg = M - 1;
            __builtin_amdgcn_global_load_lds(
                (const __attribute__((address_space(1))) uint32*)(A + (size_t)rg * 256 + k0 + gq * 8),
                (__attribute__((address_space(3))) uint32*)(As + row * 64 + (tid & 7) * 8), 16, 0, 0);
        }
        #pragma unroll
        for (int i = 0; i < 2; i++) {
            int row = i * 32 + (tid >> 3);
            int gq = (tid & 7) ^ (row & 7);
            __builtin_amdgcn_global_load_lds(
                (const __attribute__((address_space(1))) uint32*)(Bt + (size_t)row * 256 + k0 + gq * 8),
                (__attribute__((address_space(3))) uint32*)(Bs + row * 64 + (tid & 7) * 8), 16, 0, 0);
        }
        __syncthreads();
        #pragma unroll
        for (int ks = 0; ks < 2; ks++) {
            bf16x8 a[4], b[2];
            #pragma unroll
            for (int m = 0; m < 4; m++) {
                int arow = wr * 64 + m * 16 + (l & 15);
                int ag = (ks * 4 + (l >> 4)) ^ (arow & 7);
                a[m] = *(const bf16x8*)(As + arow * 64 + ag * 8);
            }
            #pragma unroll
            for (int n = 0; n < 2; n++) {
                int brow = wc * 32 + n * 16 + (l & 15);
                int bg = (ks * 4 + (l >> 4)) ^ (brow & 7);
                b[n] = *(const bf16x8*)(Bs + brow * 64 + bg * 8);
            }
            #pragma unroll
            for (int m = 0; m < 4; m++)
                #pragma unroll
                for (int n = 0; n < 2; n++)
                    acc[m][n] = __builtin_amdgcn_mfma_f32_16x16x32_bf16(a[m], b[n], acc[m][n], 0, 0, 0);
        }
        __syncthreads();
    }
    #pragma unroll
    for (int m = 0; m < 4; m++)
        #pragma unroll
        for (int n = 0; n < 2; n++)
            #pragma unroll
            for (int r = 0; r < 4; r++) {
                int gr = m0 + wr * 64 + m * 16 + (l >> 4) * 4 + r;
                int col = wc * 32 + n * 16 + (l & 15);
                if (gr < M) out[(size_t)gr * 64 + col] = acc[m][n][r] + bias[col];
            }
}

// ---------------- aggregation: 2 nodes/wave, 16B lanes, 4x edge unroll ----------------
#define ACC8(v, wgt)                                    \
    do {                                                \
        acc[0] = fmaf(wgt, bflo(v.x), acc[0]);          \
        acc[1] = fmaf(wgt, bfhi(v.x), acc[1]);          \
        acc[2] = fmaf(wgt, bflo(v.y), acc[2]);          \
        acc[3] = fmaf(wgt, bfhi(v.y), acc[3]);          \
        acc[4] = fmaf(wgt, bflo(v.z), acc[4]);          \
        acc[5] = fmaf(wgt, bfhi(v.z), acc[5]);          \
        acc[6] = fmaf(wgt, bflo(v.w), acc[6]);          \
        acc[7] = fmaf(wgt, bfhi(v.w), acc[7]);          \
    } while (0)

__global__ __launch_bounds__(256) void aggregate_bf(const unsigned short* __restrict__ t,
                                                    const float* __restrict__ dinv,
                                                    const int* __restrict__ row_ptr,
                                                    const int* __restrict__ col_idx,
                                                    const float* __restrict__ edge_w,
                                                    const float* __restrict__ bias,
                                                    unsigned short* __restrict__ outb,
                                                    int N) {
    int wave = threadIdx.x >> 6;
    int lane = threadIdx.x & 63;
    int half = lane >> 5;          // which node of the pair
    int sl = lane & 31;            // owns feats [sl*8, sl*8+8)
    int n = blockIdx.x * 8 + wave * 2 + half;
    if (n >= N) return;

    float dn = dinv[n];
    int r0 = row_ptr[n], r1 = row_ptr[n + 1];

    float acc[8];
    {
        uint4 sv = *(const uint4*)(t + (size_t)n * DH + sl * 8);
        float sn = dn * dn;
        acc[0] = bflo(sv.x) * sn; acc[1] = bfhi(sv.x) * sn;
        acc[2] = bflo(sv.y) * sn; acc[3] = bfhi(sv.y) * sn;
        acc[4] = bflo(sv.z) * sn; acc[5] = bfhi(sv.z) * sn;
        acc[6] = bflo(sv.w) * sn; acc[7] = bfhi(sv.w) * sn;
    }

    int j = r0;
    for (; j + 4 <= r1; j += 4) {
        int s0 = col_idx[j + 0], s1 = col_idx[j + 1];
        int s2 = col_idx[j + 2], s3 = col_idx[j + 3];
        float w0 = edge_w[j + 0], w1 = edge_w[j + 1];
        float w2 = edge_w[j + 2], w3 = edge_w[j + 3];
        uint4 v0 = *(const uint4*)(t + (size_t)s0 * DH + sl * 8);
        uint4 v1 = *(const uint4*)(t + (size_t)s1 * DH + sl * 8);
        uint4 v2 = *(const uint4*)(t + (size_t)s2 * DH + sl * 8);
        uint4 v3 = *(const uint4*)(t + (size_t)s3 * DH + sl * 8);
        ACC8(v0, w0); ACC8(v1, w1); ACC8(v2, w2); ACC8(v3, w3);
    }
    for (; j < r1; j++) {
        int s = col_idx[j];
        float wgt = edge_w[j];
        uint4 v = *(const uint4*)(t + (size_t)s * DH + sl * 8);
        ACC8(v, wgt);
    }

    float4 b0 = *(const float4*)(bias + sl * 8);
    float4 b1v = *(const float4*)(bias + sl * 8 + 4);
    acc[0] = fmaxf(acc[0] + b0.x, 0.f);  acc[1] = fmaxf(acc[1] + b0.y, 0.f);
    acc[2] = fmaxf(acc[2] + b0.z, 0.f);  acc[3] = fmaxf(acc[3] + b0.w, 0.f);
    acc[4] = fmaxf(acc[4] + b1v.x, 0.f); acc[5] = fmaxf(acc[5] + b1v.y, 0.f);
    acc[6] = fmaxf(acc[6] + b1v.z, 0.f); acc[7] = fmaxf(acc[7] + b1v.w, 0.f);

    uint4 o;
    o.x = pk2(acc[0], acc[1]);
    o.y = pk2(acc[2], acc[3]);
    o.z = pk2(acc[4], acc[5]);
    o.w = pk2(acc[6], acc[7]);
    *(uint4*)(outb + (size_t)n * DH + sl * 8) = o;
}

// ---------------- launch ----------------
extern "C" void kernel_launch(void* const* d_in, const int* in_sizes, int n_in,
                              void* d_out, int out_size, void* d_ws, size_t ws_size,
                              hipStream_t stream) {
    const float* x  = (const float*)d_in[0];
    const void*  ei = d_in[1];
    const float* W1 = (const float*)d_in[2];
    const float* b1 = (const float*)d_in[3];
    const float* W2 = (const float*)d_in[4];
    const float* b2 = (const float*)d_in[5];
    const float* Wc = (const float*)d_in[6];
    const float* bc = (const float*)d_in[7];
    float* out = (float*)d_out;

    const int N = in_sizes[0] / DIN;   // 100000
    const int E = in_sizes[1] / 2;     // 800000

    char* ws = (char*)d_ws;
    size_t off = 0;
    auto alloc = [&](size_t bytes) -> void* {
        off = (off + 255) & ~(size_t)255;
        void* p = ws + off;
        off += bytes;
        return p;
    };

    int*   flag      = (int*)alloc(4);
    int*   counts    = (int*)alloc((size_t)N * 4);
    int*   row_ptr   = (int*)alloc((size_t)(N + 1) * 4);
    int*   col_idx   = (int*)alloc((size_t)E * 4);
    float* edge_w    = (float*)alloc((size_t)E * 4);
    int*   blocksums = (int*)alloc(1024 * 4);
    float* dinv      = (float*)alloc((size_t)N * 4);
    unsigned short* Bt1   = (unsigned short*)alloc((size_t)DH * DIN * 2);
    unsigned short* Bt2   = (unsigned short*)alloc((size_t)DH * DH * 2);
    unsigned short* Btc   = (unsigned short*)alloc((size_t)DOUT * DH * 2);
    unsigned short* t_buf = (unsigned short*)alloc((size_t)N * DH * 2);
    unsigned short* a_buf = (unsigned short*)alloc((size_t)N * DH * 2);

    const int NB = (N + SCAN_ELEMS - 1) / SCAN_ELEMS;
    const int gM64  = (N + 63) / 64;
    const int gM128 = (N + 127) / 128;

    // dtype detection + weight prep
    detect_i64<<<1, 256, 0, stream>>>((const unsigned long long*)ei, 1024,
                                      (unsigned long long)N, flag);
    transpose_w<<<(DIN * DH + 255) / 256, 256, 0, stream>>>(W1, Bt1, DIN, DH);
    transpose_w<<<(DH * DH + 255) / 256, 256, 0, stream>>>(W2, Bt2, DH, DH);
    transpose_w<<<(DH * DOUT + 255) / 256, 256, 0, stream>>>(Wc, Btc, DH, DOUT);

    // degrees + CSR (+ per-edge weights)
    hipMemsetAsync(counts, 0, (size_t)N * 4, stream);
    count_deg<<<(E + 255) / 256, 256, 0, stream>>>(ei, flag, E, counts);
    compute_dinv<<<(N + 255) / 256, 256, 0, stream>>>(counts, dinv, N);
    scan1<<<NB, SCAN_BLOCK, 0, stream>>>(counts, row_ptr, blocksums, N);
    scan2<<<1, SCAN_BLOCK, 0, stream>>>(blocksums, NB);
    scan3<<<(N + 1 + 255) / 256, 256, 0, stream>>>(row_ptr, blocksums, N, E);
    hipMemsetAsync(counts, 0, (size_t)N * 4, stream);
    fill_csr<<<(E + 255) / 256, 256, 0, stream>>>(ei, flag, E, row_ptr, counts, col_idx,
                                                  dinv, edge_w);

    // layer 1
    gemm_mfma<true><<<gM64, 256, 0, stream>>>(x, Bt1, t_buf, N, DIN);
    aggregate_bf<<<(N + 7) / 8, 256, 0, stream>>>(t_buf, dinv, row_ptr, col_idx, edge_w, b1, a_buf, N);
    // layer 2
    gemm_mfma<false><<<gM64, 256, 0, stream>>>(a_buf, Bt2, t_buf, N, DH);
    aggregate_bf<<<(N + 7) / 8, 256, 0, stream>>>(t_buf, dinv, row_ptr, col_idx, edge_w, b2, a_buf, N);
    // head
    gemm_head<<<gM128, 256, 0, stream>>>(a_buf, Btc, bc, out, N);
}

// Round 7
// 356.576 us; speedup vs baseline: 1.2555x; 1.0862x over previous
//
#include <hip/hip_runtime.h>
#include <cstdint>

#define DIN 512
#define DH  256
#define DOUT 64

typedef __attribute__((ext_vector_type(8))) short bf16x8;
typedef __attribute__((ext_vector_type(4))) float f32x4;
typedef unsigned int uint32;

__device__ __forceinline__ unsigned short f2bf(float f) {
    uint32 u = __float_as_uint(f);
    u += 0x7fff + ((u >> 16) & 1);          // RNE
    return (unsigned short)(u >> 16);
}
__device__ __forceinline__ float bflo(uint32 u) { return __uint_as_float(u << 16); }
__device__ __forceinline__ float bfhi(uint32 u) { return __uint_as_float(u & 0xffff0000u); }
__device__ __forceinline__ uint32 pk2(float lo, float hi) {
    return (uint32)f2bf(lo) | ((uint32)f2bf(hi) << 16);
}

// ---------------- edge_index dtype detection ----------------
__global__ void detect_i64(const unsigned long long* ei, int n_check,
                           unsigned long long bound, int* flag) {
    __shared__ int ok;
    if (threadIdx.x == 0) ok = 1;
    __syncthreads();
    int bad = 0;
    for (int i = threadIdx.x; i < n_check; i += blockDim.x) {
        if (ei[i] >= bound) bad = 1;
    }
    if (bad) ok = 0;
    __syncthreads();
    if (threadIdx.x == 0) *flag = ok;
}

__device__ __forceinline__ int get_idx(const void* ei, int is64, int pos) {
    if (is64) return (int)((const long long*)ei)[pos];
    return ((const int*)ei)[pos];
}

// ---------------- degree count / dinv ----------------
__global__ void count_deg(const void* ei, const int* flag, int E, int* counts) {
    const int is64 = *flag;
    int e = blockIdx.x * blockDim.x + threadIdx.x;
    if (e >= E) return;
    int d = get_idx(ei, is64, E + e);
    atomicAdd(&counts[d], 1);
}

__global__ void compute_dinv(const int* counts, float* dinv, int N) {
    int i = blockIdx.x * blockDim.x + threadIdx.x;
    if (i < N) dinv[i] = rsqrtf((float)counts[i] + 1.0f);
}

// ---------------- exclusive scan ----------------
#define SCAN_BLOCK 256
#define SCAN_ELEMS 1024

__global__ void scan1(const int* counts, int* out, int* blocksums, int N) {
    __shared__ int sh[SCAN_BLOCK];
    int base = blockIdx.x * SCAN_ELEMS;
    int t = threadIdx.x;
    int v[4];
    int s = 0;
    #pragma unroll
    for (int j = 0; j < 4; j++) {
        int idx = base + t * 4 + j;
        v[j] = (idx < N) ? counts[idx] : 0;
        s += v[j];
    }
    sh[t] = s;
    __syncthreads();
    for (int off = 1; off < SCAN_BLOCK; off <<= 1) {
        int x = (t >= off) ? sh[t - off] : 0;
        __syncthreads();
        sh[t] += x;
        __syncthreads();
    }
    int run = (t == 0) ? 0 : sh[t - 1];
    #pragma unroll
    for (int j = 0; j < 4; j++) {
        int idx = base + t * 4 + j;
        if (idx < N) out[idx] = run;
        run += v[j];
    }
    if (t == SCAN_BLOCK - 1) blocksums[blockIdx.x] = sh[t];
}

__global__ void scan2(int* blocksums, int NB) {
    __shared__ int sh[SCAN_BLOCK];
    int t = threadIdx.x;
    sh[t] = (t < NB) ? blocksums[t] : 0;
    __syncthreads();
    for (int off = 1; off < SCAN_BLOCK; off <<= 1) {
        int x = (t >= off) ? sh[t - off] : 0;
        __syncthreads();
        sh[t] += x;
        __syncthreads();
    }
    if (t < NB) blocksums[t] = (t == 0) ? 0 : sh[t - 1];
}

__global__ void scan3(int* row_ptr, const int* blocksums, int N, int E) {
    int i = blockIdx.x * blockDim.x + threadIdx.x;
    if (i < N) row_ptr[i] += blocksums[i / SCAN_ELEMS];
    if (i == N) row_ptr[N] = E;
}

// ---------------- CSR fill (+ per-edge weight) ----------------
__global__ void fill_csr(const void* ei, const int* flag, int E,
                         const int* row_ptr, int* cursor, int* col_idx,
                         const float* dinv, float* edge_w) {
    const int is64 = *flag;
    int e = blockIdx.x * blockDim.x + threadIdx.x;
    if (e >= E) return;
    int d = get_idx(ei, is64, E + e);
    int s = get_idx(ei, is64, e);
    int pos = row_ptr[d] + atomicAdd(&cursor[d], 1);
    col_idx[pos] = s;
    edge_w[pos] = dinv[s] * dinv[d];
}

// ---------------- weight transpose+convert: W[K][Nw] f32 -> Bt[Nw][K] bf16 ----------------
__global__ void transpose_w(const float* __restrict__ W, unsigned short* __restrict__ Bt,
                            int K, int Nw) {
    int i = blockIdx.x * blockDim.x + threadIdx.x;
    if (i >= K * Nw) return;
    int k = i / Nw, n = i % Nw;
    Bt[(size_t)n * K + k] = f2bf(W[i]);
}

// ---------------- GEMM1 (round-4 structure): C[M,256]=A[M,K]*Bt[256,K]^T ----------------
// BM=64 BN=256 BK=64, 256 threads (4 waves). A+B staged, XOR-swizzled LDS.
template <bool A_FP32>
__global__ __launch_bounds__(256) void gemm_mfma(const void* __restrict__ Ap,
                                                 const unsigned short* __restrict__ Bt,
                                                 unsigned short* __restrict__ C,
                                                 int M, int K) {
    __shared__ unsigned short lds[20480];   // As[64][64] | Bs[256][64] = 40 KB
    unsigned short* As = lds;
    unsigned short* Bs = lds + 4096;
    const int tid = threadIdx.x;
    const int w = tid >> 6, l = tid & 63;
    const int m0 = blockIdx.x * 64;

    f32x4 acc[4][4] = {};

    for (int k0 = 0; k0 < K; k0 += 64) {
        // ---- stage B: 256x64 bf16, source granule pre-swizzled ----
        #pragma unroll
        for (int i = 0; i < 8; i++) {
            int row = i * 32 + (tid >> 3);
            int gq = (tid & 7) ^ (row & 7);
            const unsigned short* src = Bt + (size_t)row * K + k0 + gq * 8;
            unsigned short* dst = Bs + row * 64 + (tid & 7) * 8;
            __builtin_amdgcn_global_load_lds(
                (const __attribute__((address_space(1))) uint32*)src,
                (__attribute__((address_space(3))) uint32*)dst, 16, 0, 0);
        }
        // ---- stage A: 64x64 ----
        if (A_FP32) {
            const float* Af = (const float*)Ap;
            #pragma unroll
            for (int i = 0; i < 2; i++) {
                int row = i * 32 + (tid >> 3);
                int g = tid & 7;
                int rg = m0 + row; if (rg > M - 1) rg = M - 1;
                const float* s = Af + (size_t)rg * K + k0 + g * 8;
                float4 v0 = *(const float4*)s;
                float4 v1 = *(const float4*)(s + 4);
                uint4 o;
                o.x = pk2(v0.x, v0.y); o.y = pk2(v0.z, v0.w);
                o.z = pk2(v1.x, v1.y); o.w = pk2(v1.z, v1.w);
                *(uint4*)(As + row * 64 + ((g ^ (row & 7)) * 8)) = o;
            }
        } else {
            const unsigned short* Ab = (const unsigned short*)Ap;
            #pragma unroll
            for (int i = 0; i < 2; i++) {
                int row = i * 32 + (tid >> 3);
                int gq = (tid & 7) ^ (row & 7);
                int rg = m0 + row; if (rg > M - 1) rg = M - 1;
                const unsigned short* src = Ab + (size_t)rg * K + k0 + gq * 8;
                unsigned short* dst = As + row * 64 + (tid & 7) * 8;
                __builtin_amdgcn_global_load_lds(
                    (const __attribute__((address_space(1))) uint32*)src,
                    (__attribute__((address_space(3))) uint32*)dst, 16, 0, 0);
            }
        }
        __syncthreads();
        // ---- compute (swizzled ds_read) ----
        #pragma unroll
        for (int ks = 0; ks < 2; ks++) {
            bf16x8 a[4], b[4];
            #pragma unroll
            for (int m = 0; m < 4; m++) {
                int arow = m * 16 + (l & 15);
                int ag = (ks * 4 + (l >> 4)) ^ (arow & 7);
                a[m] = *(const bf16x8*)(As + arow * 64 + ag * 8);
            }
            #pragma unroll
            for (int n = 0; n < 4; n++) {
                int brow = w * 64 + n * 16 + (l & 15);
                int bg = (ks * 4 + (l >> 4)) ^ (brow & 7);
                b[n] = *(const bf16x8*)(Bs + brow * 64 + bg * 8);
            }
            #pragma unroll
            for (int m = 0; m < 4; m++)
                #pragma unroll
                for (int n = 0; n < 4; n++)
                    acc[m][n] = __builtin_amdgcn_mfma_f32_16x16x32_bf16(a[m], b[n], acc[m][n], 0, 0, 0);
        }
        __syncthreads();
    }

    // ---- epilogue: per-wave 64x64 region -> coalesced 16B stores ----
    unsigned short* ep = lds + w * 4096;
    #pragma unroll
    for (int m = 0; m < 4; m++)
        #pragma unroll
        for (int n = 0; n < 4; n++)
            #pragma unroll
            for (int r = 0; r < 4; r++)
                ep[(m * 16 + (l >> 4) * 4 + r) * 64 + n * 16 + (l & 15)] = f2bf(acc[m][n][r]);
    __syncthreads();
    #pragma unroll
    for (int p = 0; p < 8; p++) {
        int row = p * 8 + (l >> 3);
        int gr = m0 + row;
        uint4 v = *(const uint4*)(ep + row * 64 + (l & 7) * 8);
        if (gr < M)
            *(uint4*)(C + (size_t)gr * 256 + w * 64 + (l & 7) * 8) = v;
    }
}

// ---------------- GEMM2 persistent-B: C[M,256] = A[M,256] @ Bt[256,256]^T ----------------
// 512 threads (8 waves, 2x4). Whole Bt2 (128 KB) LDS-resident, loaded once.
// A streamed through 2x8KB dbuf, one barrier per K-step. Grid-stride M-tiles of 64.
__global__ __launch_bounds__(512) void gemm2_persist(const unsigned short* __restrict__ A,
                                                     const unsigned short* __restrict__ Bt,
                                                     unsigned short* __restrict__ C,
                                                     int M) {
    __shared__ unsigned short lds[73728];   // Bs 128 KB + As 2x8 KB = 144 KB
    unsigned short* Bs = lds;               // [256 rows(n)][256 cols(k)], swizzled granules
    unsigned short* As = lds + 65536;       // 2 bufs of 4096 ushorts ([64][64])
    const int tid = threadIdx.x;
    const int w = tid >> 6, l = tid & 63;
    const int wr = w >> 2, wc = w & 3;      // 2 x 4 wave grid

    // ---- load ALL of Bt once (8192 granules of 16B; 16 per thread) ----
    #pragma unroll
    for (int i = 0; i < 16; i++) {
        int gi = i * 512 + tid;             // 0..8191
        int r = gi >> 5, g = gi & 31;       // row, dest granule (32 granules/row)
        int gs = g ^ (r & 7);               // pre-swizzled source granule
        __builtin_amdgcn_global_load_lds(
            (const __attribute__((address_space(1))) uint32*)(Bt + (size_t)r * 256 + gs * 8),
            (__attribute__((address_space(3))) uint32*)(Bs + (size_t)gi * 8), 16, 0, 0);
    }

    const int sr = tid >> 3;                // A-stage row 0..63
    const int sg = tid & 7;                 // A-stage dest granule

    for (int mt = blockIdx.x; mt * 64 < M; mt += gridDim.x) {
        const int m0 = mt * 64;
        // stage A(k=0) into buf 0
        {
            int rg = m0 + sr; if (rg > M - 1) rg = M - 1;
            int gq = sg ^ (sr & 7);
            __builtin_amdgcn_global_load_lds(
                (const __attribute__((address_space(1))) uint32*)(A + (size_t)rg * 256 + gq * 8),
                (__attribute__((address_space(3))) uint32*)(As + tid * 8), 16, 0, 0);
        }
        __syncthreads();                    // drains B-load too on first tile

        f32x4 acc[2][4] = {};
        #pragma unroll
        for (int k = 0; k < 4; k++) {
            if (k < 3) {                    // prefetch next A chunk into other buf
                int rg = m0 + sr; if (rg > M - 1) rg = M - 1;
                int gq = sg ^ (sr & 7);
                __builtin_amdgcn_global_load_lds(
                    (const __attribute__((address_space(1))) uint32*)(A + (size_t)rg * 256 + (k + 1) * 64 + gq * 8),
                    (__attribute__((address_space(3))) uint32*)(As + ((k + 1) & 1) * 4096 + tid * 8), 16, 0, 0);
            }
            const unsigned short* Ab = As + (k & 1) * 4096;
            #pragma unroll
            for (int ks = 0; ks < 2; ks++) {
                bf16x8 a[2], b[4];
                #pragma unroll
                for (int m = 0; m < 2; m++) {
                    int ar = wr * 32 + m * 16 + (l & 15);
                    int q = (ks * 4 + (l >> 4)) ^ (ar & 7);
                    a[m] = *(const bf16x8*)(Ab + ar * 64 + q * 8);
                }
                #pragma unroll
                for (int n = 0; n < 4; n++) {
                    int br = wc * 64 + n * 16 + (l & 15);
                    int gabs = k * 8 + ks * 4 + (l >> 4);
                    int q = gabs ^ (br & 7);
                    b[n] = *(const bf16x8*)(Bs + br * 256 + q * 8);
                }
                #pragma unroll
                for (int m = 0; m < 2; m++)
                    #pragma unroll
                    for (int n = 0; n < 4; n++)
                        acc[m][n] = __builtin_amdgcn_mfma_f32_16x16x32_bf16(a[m], b[n], acc[m][n], 0, 0, 0);
            }
            __syncthreads();                // frees read buf; waits prefetch
        }

        // epilogue: direct global stores (16 lanes x 2B = 32B chunks, L2-combined)
        #pragma unroll
        for (int m = 0; m < 2; m++)
            #pragma unroll
            for (int r = 0; r < 4; r++) {
                int row = m0 + wr * 32 + m * 16 + (l >> 4) * 4 + r;
                if (row >= M) continue;
                #pragma unroll
                for (int n = 0; n < 4; n++) {
                    int col = wc * 64 + n * 16 + (l & 15);
                    C[(size_t)row * 256 + col] = f2bf(acc[m][n][r]);
                }
            }
    }
}

// ---------------- head GEMM: out[M,64] = A[M,256]*Bt[64,256]^T + bias, f32 out ----------------
__global__ __launch_bounds__(256) void gemm_head(const unsigned short* __restrict__ A,
                                                 const unsigned short* __restrict__ Bt,
                                                 const float* __restrict__ bias,
                                                 float* __restrict__ out, int M) {
    __shared__ unsigned short As[128 * 64];
    __shared__ unsigned short Bs[64 * 64];
    const int tid = threadIdx.x;
    const int w = tid >> 6, l = tid & 63;
    const int m0 = blockIdx.x * 128;
    const int wr = w >> 1, wc = w & 1;
    f32x4 acc[4][2] = {};

    for (int k0 = 0; k0 < 256; k0 += 64) {
        #pragma unroll
        for (int i = 0; i < 4; i++) {
            int row = i * 32 + (tid >> 3);
            int gq = (tid & 7) ^ (row & 7);
            int rg = m0 + row; if (rg > M - 1) rg = M - 1;
            __builtin_amdgcn_global_load_lds(
                (const __attribute__((address_space(1))) uint32*)(A + (size_t)rg * 256 + k0 + gq * 8),
                (__attribute__((address_space(3))) uint32*)(As + row * 64 + (tid & 7) * 8), 16, 0, 0);
        }
        #pragma unroll
        for (int i = 0; i < 2; i++) {
            int row = i * 32 + (tid >> 3);
            int gq = (tid & 7) ^ (row & 7);
            __builtin_amdgcn_global_load_lds(
                (const __attribute__((address_space(1))) uint32*)(Bt + (size_t)row * 256 + k0 + gq * 8),
                (__attribute__((address_space(3))) uint32*)(Bs + row * 64 + (tid & 7) * 8), 16, 0, 0);
        }
        __syncthreads();
        #pragma unroll
        for (int ks = 0; ks < 2; ks++) {
            bf16x8 a[4], b[2];
            #pragma unroll
            for (int m = 0; m < 4; m++) {
                int arow = wr * 64 + m * 16 + (l & 15);
                int ag = (ks * 4 + (l >> 4)) ^ (arow & 7);
                a[m] = *(const bf16x8*)(As + arow * 64 + ag * 8);
            }
            #pragma unroll
            for (int n = 0; n < 2; n++) {
                int brow = wc * 32 + n * 16 + (l & 15);
                int bg = (ks * 4 + (l >> 4)) ^ (brow & 7);
                b[n] = *(const bf16x8*)(Bs + brow * 64 + bg * 8);
            }
            #pragma unroll
            for (int m = 0; m < 4; m++)
                #pragma unroll
                for (int n = 0; n < 2; n++)
                    acc[m][n] = __builtin_amdgcn_mfma_f32_16x16x32_bf16(a[m], b[n], acc[m][n], 0, 0, 0);
        }
        __syncthreads();
    }
    #pragma unroll
    for (int m = 0; m < 4; m++)
        #pragma unroll
        for (int n = 0; n < 2; n++)
            #pragma unroll
            for (int r = 0; r < 4; r++) {
                int gr = m0 + wr * 64 + m * 16 + (l >> 4) * 4 + r;
                int col = wc * 32 + n * 16 + (l & 15);
                if (gr < M) out[(size_t)gr * 64 + col] = acc[m][n][r] + bias[col];
            }
}

// ---------------- aggregation: 2 nodes/wave, 16B lanes, 4x edge unroll ----------------
#define ACC8(v, wgt)                                    \
    do {                                                \
        acc[0] = fmaf(wgt, bflo(v.x), acc[0]);          \
        acc[1] = fmaf(wgt, bfhi(v.x), acc[1]);          \
        acc[2] = fmaf(wgt, bflo(v.y), acc[2]);          \
        acc[3] = fmaf(wgt, bfhi(v.y), acc[3]);          \
        acc[4] = fmaf(wgt, bflo(v.z), acc[4]);          \
        acc[5] = fmaf(wgt, bfhi(v.z), acc[5]);          \
        acc[6] = fmaf(wgt, bflo(v.w), acc[6]);          \
        acc[7] = fmaf(wgt, bfhi(v.w), acc[7]);          \
    } while (0)

__global__ __launch_bounds__(256) void aggregate_bf(const unsigned short* __restrict__ t,
                                                    const float* __restrict__ dinv,
                                                    const int* __restrict__ row_ptr,
                                                    const int* __restrict__ col_idx,
                                                    const float* __restrict__ edge_w,
                                                    const float* __restrict__ bias,
                                                    unsigned short* __restrict__ outb,
                                                    int N) {
    int wave = threadIdx.x >> 6;
    int lane = threadIdx.x & 63;
    int half = lane >> 5;          // which node of the pair
    int sl = lane & 31;            // owns feats [sl*8, sl*8+8)
    int n = blockIdx.x * 8 + wave * 2 + half;
    if (n >= N) return;

    float dn = dinv[n];
    int r0 = row_ptr[n], r1 = row_ptr[n + 1];

    float acc[8];
    {
        uint4 sv = *(const uint4*)(t + (size_t)n * DH + sl * 8);
        float sn = dn * dn;
        acc[0] = bflo(sv.x) * sn; acc[1] = bfhi(sv.x) * sn;
        acc[2] = bflo(sv.y) * sn; acc[3] = bfhi(sv.y) * sn;
        acc[4] = bflo(sv.z) * sn; acc[5] = bfhi(sv.z) * sn;
        acc[6] = bflo(sv.w) * sn; acc[7] = bfhi(sv.w) * sn;
    }

    int j = r0;
    for (; j + 4 <= r1; j += 4) {
        int s0 = col_idx[j + 0], s1 = col_idx[j + 1];
        int s2 = col_idx[j + 2], s3 = col_idx[j + 3];
        float w0 = edge_w[j + 0], w1 = edge_w[j + 1];
        float w2 = edge_w[j + 2], w3 = edge_w[j + 3];
        uint4 v0 = *(const uint4*)(t + (size_t)s0 * DH + sl * 8);
        uint4 v1 = *(const uint4*)(t + (size_t)s1 * DH + sl * 8);
        uint4 v2 = *(const uint4*)(t + (size_t)s2 * DH + sl * 8);
        uint4 v3 = *(const uint4*)(t + (size_t)s3 * DH + sl * 8);
        ACC8(v0, w0); ACC8(v1, w1); ACC8(v2, w2); ACC8(v3, w3);
    }
    for (; j < r1; j++) {
        int s = col_idx[j];
        float wgt = edge_w[j];
        uint4 v = *(const uint4*)(t + (size_t)s * DH + sl * 8);
        ACC8(v, wgt);
    }

    float4 b0 = *(const float4*)(bias + sl * 8);
    float4 b1v = *(const float4*)(bias + sl * 8 + 4);
    acc[0] = fmaxf(acc[0] + b0.x, 0.f);  acc[1] = fmaxf(acc[1] + b0.y, 0.f);
    acc[2] = fmaxf(acc[2] + b0.z, 0.f);  acc[3] = fmaxf(acc[3] + b0.w, 0.f);
    acc[4] = fmaxf(acc[4] + b1v.x, 0.f); acc[5] = fmaxf(acc[5] + b1v.y, 0.f);
    acc[6] = fmaxf(acc[6] + b1v.z, 0.f); acc[7] = fmaxf(acc[7] + b1v.w, 0.f);

    uint4 o;
    o.x = pk2(acc[0], acc[1]);
    o.y = pk2(acc[2], acc[3]);
    o.z = pk2(acc[4], acc[5]);
    o.w = pk2(acc[6], acc[7]);
    *(uint4*)(outb + (size_t)n * DH + sl * 8) = o;
}

// ---------------- launch ----------------
extern "C" void kernel_launch(void* const* d_in, const int* in_sizes, int n_in,
                              void* d_out, int out_size, void* d_ws, size_t ws_size,
                              hipStream_t stream) {
    const float* x  = (const float*)d_in[0];
    const void*  ei = d_in[1];
    const float* W1 = (const float*)d_in[2];
    const float* b1 = (const float*)d_in[3];
    const float* W2 = (const float*)d_in[4];
    const float* b2 = (const float*)d_in[5];
    const float* Wc = (const float*)d_in[6];
    const float* bc = (const float*)d_in[7];
    float* out = (float*)d_out;

    const int N = in_sizes[0] / DIN;   // 100000
    const int E = in_sizes[1] / 2;     // 800000

    char* ws = (char*)d_ws;
    size_t off = 0;
    auto alloc = [&](size_t bytes) -> void* {
        off = (off + 255) & ~(size_t)255;
        void* p = ws + off;
        off += bytes;
        return p;
    };

    int*   flag      = (int*)alloc(4);
    int*   counts    = (int*)alloc((size_t)N * 4);
    int*   row_ptr   = (int*)alloc((size_t)(N + 1) * 4);
    int*   col_idx   = (int*)alloc((size_t)E * 4);
    float* edge_w    = (float*)alloc((size_t)E * 4);
    int*   blocksums = (int*)alloc(1024 * 4);
    float* dinv      = (float*)alloc((size_t)N * 4);
    unsigned short* Bt1   = (unsigned short*)alloc((size_t)DH * DIN * 2);
    unsigned short* Bt2   = (unsigned short*)alloc((size_t)DH * DH * 2);
    unsigned short* Btc   = (unsigned short*)alloc((size_t)DOUT * DH * 2);
    unsigned short* t_buf = (unsigned short*)alloc((size_t)N * DH * 2);
    unsigned short* a_buf = (unsigned short*)alloc((size_t)N * DH * 2);

    const int NB = (N + SCAN_ELEMS - 1) / SCAN_ELEMS;
    const int gM64  = (N + 63) / 64;
    const int gM128 = (N + 127) / 128;

    // dtype detection + weight prep
    detect_i64<<<1, 256, 0, stream>>>((const unsigned long long*)ei, 1024,
                                      (unsigned long long)N, flag);
    transpose_w<<<(DIN * DH + 255) / 256, 256, 0, stream>>>(W1, Bt1, DIN, DH);
    transpose_w<<<(DH * DH + 255) / 256, 256, 0, stream>>>(W2, Bt2, DH, DH);
    transpose_w<<<(DH * DOUT + 255) / 256, 256, 0, stream>>>(Wc, Btc, DH, DOUT);

    // degrees + CSR (+ per-edge weights)
    hipMemsetAsync(counts, 0, (size_t)N * 4, stream);
    count_deg<<<(E + 255) / 256, 256, 0, stream>>>(ei, flag, E, counts);
    compute_dinv<<<(N + 255) / 256, 256, 0, stream>>>(counts, dinv, N);
    scan1<<<NB, SCAN_BLOCK, 0, stream>>>(counts, row_ptr, blocksums, N);
    scan2<<<1, SCAN_BLOCK, 0, stream>>>(blocksums, NB);
    scan3<<<(N + 1 + 255) / 256, 256, 0, stream>>>(row_ptr, blocksums, N, E);
    hipMemsetAsync(counts, 0, (size_t)N * 4, stream);
    fill_csr<<<(E + 255) / 256, 256, 0, stream>>>(ei, flag, E, row_ptr, counts, col_idx,
                                                  dinv, edge_w);

    // layer 1
    gemm_mfma<true><<<gM64, 256, 0, stream>>>(x, Bt1, t_buf, N, DIN);
    aggregate_bf<<<(N + 7) / 8, 256, 0, stream>>>(t_buf, dinv, row_ptr, col_idx, edge_w, b1, a_buf, N);
    // layer 2 (persistent-B)
    gemm2_persist<<<256, 512, 0, stream>>>(a_buf, Bt2, t_buf, N);
    aggregate_bf<<<(N + 7) / 8, 256, 0, stream>>>(t_buf, dinv, row_ptr, col_idx, edge_w, b2, a_buf, N);
    // head
    gemm_head<<<gM128, 256, 0, stream>>>(a_buf, Btc, bc, out, N);
}